// Round 5
// baseline (398.029 us; speedup 1.0000x reference)
//
#include <hip/hip_runtime.h>
#include <stdint.h>

#define HID 128
#define NNODES 50000
#define NEDGES 800000
#define WPL 98304   // bf16 weight elems per layer in wt scratch
#define NPAD 50176  // padded node count (= 196*256 = 49*1024)

typedef __attribute__((ext_vector_type(8))) short short8;
typedef __attribute__((ext_vector_type(4))) float floatx4;
typedef __attribute__((ext_vector_type(2))) float f32x2;

__device__ __forceinline__ float bf2f(unsigned short h) {
    union { unsigned int u; float f; } v; v.u = ((unsigned int)h) << 16; return v.f;
}
__device__ __forceinline__ unsigned short f2bf(float f) {
    union { float f; unsigned int u; } v; v.f = f;
    unsigned int u = v.u;
    return (unsigned short)((u + 0x7fffu + ((u >> 16) & 1u)) >> 16);
}
// unpack 2 packed bf16 (one u32) -> f32x2
__device__ __forceinline__ f32x2 unpk2(unsigned int w) {
    union { unsigned int u; float f; } a, b;
    a.u = w << 16; b.u = w & 0xffff0000u;
    f32x2 r; r.x = a.f; r.y = b.f; return r;
}
__device__ __forceinline__ f32x2 pkmax0(f32x2 a) {
    f32x2 r; r.x = fmaxf(a.x, 0.f); r.y = fmaxf(a.y, 0.f); return r;
}

// ---- merged: convert all layer weights to bf16 (transposed [n][k]) + edge histogram ----
__global__ __launch_bounds__(256) void cvt_hist_k(
    const float* __restrict__ mW1, const float* __restrict__ mW2,
    const float* __restrict__ uW1, const float* __restrict__ uW2,
    unsigned short* __restrict__ wt,
    const int* __restrict__ dst, int* __restrict__ cnt, int* __restrict__ rank)
{
    if (blockIdx.x < 3125) {
        int e = blockIdx.x * 256 + threadIdx.x;
        rank[e] = atomicAdd(&cnt[dst[e]], 1);
        return;
    }
    int id = (blockIdx.x - 3125) * 256 + threadIdx.x;
    int l = id / WPL;
    int r = id - l * WPL;
    float v;
    if (r < 16384)      { int n = r >> 7, k = r & 127;                v = mW1[(l*257 + k)*128 + n]; }
    else if (r < 32768) { int q = r - 16384; int n = q >> 7, k = q & 127; v = mW1[(l*257 + 128 + k)*128 + n]; }
    else if (r < 49152) { int q = r - 32768; int n = q >> 7, k = q & 127; v = mW2[(l*128 + k)*128 + n]; }
    else if (r < 81920) { int q = r - 49152; int n = q >> 8, k = q & 255; v = uW1[(l*256 + k)*128 + n]; }
    else                { int q = r - 81920; int n = q >> 7, k = q & 127; v = uW2[(l*128 + k)*128 + n]; }
    wt[id] = f2bf(v);
}

// ---- merged scan1 (blocks 0..48) + prep (blocks 49..51) ----
// scan1: per-block inclusive scan of cnt -> offs, block totals -> btot
// prep: wt2[l] = (W2@U1b)^T as [n][kp]; c1f[l][n] = b2@U1b  (MFMA)
__global__ __launch_bounds__(256) void scan1prep_k(
    const int* __restrict__ cnt, int* __restrict__ offs, int* __restrict__ btot,
    const unsigned short* __restrict__ wt, const float* __restrict__ mlp_b2,
    unsigned short* __restrict__ wt2, float* __restrict__ c1f)
{
    __shared__ unsigned short Bs[128][136];
    __shared__ int wsum[4];
    int tid = threadIdx.x, lane = tid & 63, wave = tid >> 6;
    if (blockIdx.x < 49) {
        int gid = blockIdx.x * 256 + tid;
        int4 v = ((const int4*)cnt)[gid];
        int tot = v.x + v.y + v.z + v.w;
        int sc = tot;
        #pragma unroll
        for (int o = 1; o < 64; o <<= 1) {
            int t = __shfl_up(sc, o);
            if (lane >= o) sc += t;
        }
        if (lane == 63) wsum[wave] = sc;
        __syncthreads();
        int woff = 0;
        #pragma unroll
        for (int i = 0; i < 3; ++i) if (i < wave) woff += wsum[i];
        int excl = woff + sc - tot;
        int4 o;
        o.x = excl; o.y = excl + v.x; o.z = o.y + v.y; o.w = o.z + v.z;
        ((int4*)offs)[gid] = o;
        if (tid == 255) btot[blockIdx.x] = woff + sc;
        return;
    }
    // ---- prep part ----
    int l = blockIdx.x - 49;
    const unsigned short* u1bt = wt + l*WPL + 49152 + 128;  // A: [n][m], row stride 256
    const unsigned short* w2t  = wt + l*WPL + 32768;        // [m][kp], row stride 128
    int cl = lane & 15, quad = lane >> 4;
    int grow0 = wave * 32;
    floatx4 zero = {0.f,0.f,0.f,0.f};
    floatx4 acc0[8], acc1[8];
    short8 a0[4], a1[4];
    #pragma unroll
    for (int k = 0; k < 4; ++k) {
        a0[k] = *(const short8*)(u1bt + (long)(grow0 + cl)*256 + k*32 + quad*8);
        a1[k] = *(const short8*)(u1bt + (long)(grow0 + 16 + cl)*256 + k*32 + quad*8);
    }
    for (int i = 0; i < 64; ++i) {
        int idx = i*256 + tid;
        int m = idx >> 7, kp = idx & 127;
        Bs[kp][m] = w2t[m*128 + kp];
    }
    __syncthreads();
    #pragma unroll
    for (int t = 0; t < 8; ++t) { acc0[t] = zero; acc1[t] = zero; }
    #pragma unroll
    for (int k = 0; k < 4; ++k) {
        #pragma unroll
        for (int t = 0; t < 8; ++t) {
            short8 bf = *(const short8*)(&Bs[t*16 + cl][k*32 + quad*8]);
            acc0[t] = __builtin_amdgcn_mfma_f32_16x16x32_bf16(a0[k], bf, acc0[t], 0, 0, 0);
            acc1[t] = __builtin_amdgcn_mfma_f32_16x16x32_bf16(a1[k], bf, acc1[t], 0, 0, 0);
        }
    }
    #pragma unroll
    for (int t = 0; t < 8; ++t) {
        int col = t*16 + cl;
        #pragma unroll
        for (int r = 0; r < 4; ++r) {
            int n0 = grow0 + quad*4 + r, n1 = grow0 + 16 + quad*4 + r;
            wt2[(long)l*16384 + n0*128 + col] = f2bf(acc0[t][r]);
            wt2[(long)l*16384 + n1*128 + col] = f2bf(acc1[t][r]);
        }
    }
    if (tid < 128) {
        const float* mb2 = mlp_b2 + l*128;
        float acc = 0.f;
        for (int m = 0; m < 128; ++m)
            acc += mb2[m] * bf2f(u1bt[(long)tid*256 + m]);
        c1f[l*128 + tid] = acc;
    }
}

// merged scan2+3: each block reduces btot[0..blockIdx) itself, adds to its offs chunk
__global__ __launch_bounds__(256) void scan23_k(const int* __restrict__ btot, int* __restrict__ offs)
{
    __shared__ int psh;
    int tid = threadIdx.x;
    if (tid < 64) {
        int v = (tid < blockIdx.x) ? btot[tid] : 0;   // blockIdx < 49
        #pragma unroll
        for (int o = 32; o > 0; o >>= 1) v += __shfl_down(v, o);
        if (tid == 0) psh = v;
    }
    __syncthreads();
    int gid = blockIdx.x * 256 + tid;
    int p = psh;
    int4 o = ((int4*)offs)[gid];
    o.x += p; o.y += p; o.z += p; o.w += p;
    ((int4*)offs)[gid] = o;
}

// ======== macros: 128-row blocks, 8 waves (512 thr), M=16/wave, LDS-staged B ========
#define STAGE_B64(ptr, stride, k0) { __syncthreads(); _Pragma("unroll") \
    for (int it = 0; it < 4; ++it) { int idx = it*2048 + tid*4; int r = idx >> 6, c = idx & 63; \
        *(ushort4*)(&Bs[r][c]) = *(const ushort4*)((ptr) + (long)r*(stride) + (k0) + c); } \
    __syncthreads(); }
#define MFMA_L64(k0) { _Pragma("unroll") for (int kk = 0; kk < 64; kk += 32) { \
    short8 a0 = *(const short8*)(&buf[wrow + cl][(k0) + kk + quad*8]); \
    _Pragma("unroll") for (int t = 0; t < 8; ++t) { \
        short8 bf = *(const short8*)(&Bs[t*16 + cl][kk + quad*8]); \
        acc[t] = __builtin_amdgcn_mfma_f32_16x16x32_bf16(a0, bf, acc[t], 0, 0, 0); } } }
#define STAGE_BF(ptr, stride) { __syncthreads(); _Pragma("unroll") \
    for (int it = 0; it < 8; ++it) { int q = it*512 + tid; int r = q >> 5, c = (q & 31)*4; \
        *(ushort4*)(&Bs[r][c]) = *(const ushort4*)((ptr) + (long)r*(stride) + c); } \
    __syncthreads(); }
#define MFMA_R(p) { _Pragma("unroll") for (int k4 = 0; k4 < 4; ++k4) { \
    _Pragma("unroll") for (int t = 0; t < 8; ++t) { \
        short8 bf = *(const short8*)(&Bs[t*16 + cl][k4*32 + quad*8]); \
        acc[t] = __builtin_amdgcn_mfma_f32_16x16x32_bf16(p[k4], bf, acc[t], 0, 0, 0); } } }
#define LOADA_BUF16(d) { _Pragma("unroll") for (int k4 = 0; k4 < 4; ++k4) \
    d[k4] = *(const short8*)(&buf[wrow + cl][k4*32 + quad*8]); }
#define PRELOAD_A16(d, aptr, astride) { _Pragma("unroll") \
    for (int k = 0; k < 4; ++k) \
        d[k] = *(const short8*)((aptr) + (long)(grow0 + cl)*(astride) + k*32 + quad*8); }
#define ZACC8() { _Pragma("unroll") for (int t = 0; t < 8; ++t) acc[t] = zero; }

// per-edge aggregation update (accX in {a,b})
#define AGG_EDGE(word, q, accX) { \
    float vf; { union { unsigned int u; float f; } t_; t_.u = (word) & 0xffff0000u; vf = t_.f; } \
    f32x2 vv; vv.x = vf; vv.y = vf; \
    accX##01 += pkmax0(p01 + unpk2((q).x) + vv*w01); \
    accX##23 += pkmax0(p23 + unpk2((q).y) + vv*w23); }

// ---- fused encoder + PQ0 (blocks 0..390) + edge placement (blocks 391..1953) ----
__global__ __launch_bounds__(512, 4) void enc_place_k(
    const float* __restrict__ nf, const float* __restrict__ encW, const float* __restrict__ encb,
    const unsigned short* __restrict__ w1abt,   // [256][128] layer-0
    const float* __restrict__ mb1,
    unsigned short* __restrict__ u_in, unsigned short* __restrict__ PQ,
    const int* __restrict__ esrc, const int* __restrict__ edst,
    const float* __restrict__ ea, const int* __restrict__ offs,
    const int* __restrict__ rank, unsigned int* __restrict__ sorted)
{
    __shared__ unsigned short Bs[128][72];
    __shared__ unsigned short buf[128][136];
    int tid = threadIdx.x;
    if (blockIdx.x >= 391) {
        // ---- placement: pos = offs[dst[e]] + rank[e] (no atomics) ----
        int e = (blockIdx.x - 391) * 512 + tid;
        if (e < NEDGES) {
            int d = edst[e];
            int pos = offs[d] + rank[e];
            unsigned pr = ((unsigned)f2bf(ea[e]) << 16) | (unsigned)esrc[e];
            sorted[pos] = pr;
        }
        return;
    }
    int wave = tid >> 6, lane = tid & 63;
    int cl = lane & 15, quad = lane >> 4;
    int row0 = blockIdx.x * 128;
    int wrow = wave * 16;
    int grow0 = row0 + wrow;
    floatx4 zero = {0.f,0.f,0.f,0.f};
    floatx4 acc[8];

    float* nfs = (float*)&Bs[0][0];             // 640 floats = 2.5 KB (aliased; used before staging)
    for (int i = tid; i < 640; i += 512) {
        int gi = row0*5 + i;
        nfs[i] = (gi < NNODES*5) ? nf[gi] : 0.f;
    }
    __syncthreads();
    {
        int c = tid & 127, h = tid >> 7;       // h in 0..3, 32 rows each
        float w0 = encW[c], w1 = encW[128 + c], w2 = encW[256 + c], w3 = encW[384 + c], w4 = encW[512 + c];
        float bb = encb[c];
        for (int rr = 0; rr < 32; ++rr) {
            int r = h*32 + rr;
            float a = bb + nfs[r*5]*w0 + nfs[r*5+1]*w1 + nfs[r*5+2]*w2
                         + nfs[r*5+3]*w3 + nfs[r*5+4]*w4;
            unsigned short hv = f2bf(a);
            buf[r][c] = hv;
            int grow = row0 + r;
            if (grow < NNODES) u_in[(long)grow*256 + c] = hv;
        }
    }
    #pragma unroll
    for (int half = 0; half < 2; ++half) {
        ZACC8();
        STAGE_B64(w1abt + half*16384, 128, 0);   MFMA_L64(0);
        STAGE_B64(w1abt + half*16384, 128, 64);  MFMA_L64(64);
        #pragma unroll
        for (int t = 0; t < 8; ++t) {
            int col = t*16 + cl;
            float bv = (half == 0) ? mb1[col] : 0.f;
            #pragma unroll
            for (int r = 0; r < 4; ++r) {
                int g0 = grow0 + quad*4 + r;
                PQ[(long)g0*256 + half*128 + col] = f2bf(acc[t][r] + bv);
            }
        }
    }
}

// ---- fused per-layer: aggregate (own 128 nodes -> buf LDS) + update MLP + LN + next PQ ----
// PQin/PQout double-buffered: stage-C writes never race other blocks' gathers.
__global__ __launch_bounds__(512, 4) void fused_layer_k(
    const unsigned short* __restrict__ PQin,    // [50048][256] layer-l P|Q
    const unsigned int* __restrict__ sorted, const int* __restrict__ offs,
    const int* __restrict__ cnt,
    const float* __restrict__ w1c,              // [128] fp32 edge-attr column of W1
    const unsigned short* __restrict__ u1t,     // [128][256] (U1^T; k cols 0..128 = U1a)
    const unsigned short* __restrict__ wt2l,    // [128][128] (W2@U1b)^T
    const unsigned short* __restrict__ u2t,     // [128][128]
    const unsigned short* __restrict__ w1abt,   // [256][128] next-layer, or null
    const float* __restrict__ c1l,              // [128] b2@U1b
    const float* __restrict__ ub1, const float* __restrict__ ub2,
    const float* __restrict__ lng, const float* __restrict__ lnb,
    const float* __restrict__ mb1n,             // next-layer b1, or null
    unsigned short* __restrict__ u_in,          // x at stride 256 (read cols 0:128, write x')
    unsigned short* __restrict__ PQout,         // [50048][256] next-layer P|Q (if w1abt)
    float* __restrict__ sumv)                   // [128] colsum out (if !w1abt)
{
    __shared__ unsigned short Bs[128][136];     // staged B (N=128 x K=128, +pad)
    __shared__ unsigned short buf[128][136];    // aggregated Hb, then u_hid, then x' (wave-private rows)
    int tid = threadIdx.x, wave = tid >> 6, lane = tid & 63;
    int cl = lane & 15, quad = lane >> 4;
    int row0 = blockIdx.x * 128;
    int wrow = wave * 16;
    int grow0 = row0 + wrow;
    floatx4 zero = {0.f,0.f,0.f,0.f};
    floatx4 acc[8];

    // issue x preload early; latency hides under aggregation
    short8 xA[4];
    PRELOAD_A16(xA, u_in, 256);
    // pre-stage U1a so post-aggregation MFMA can start without a staging barrier
    STAGE_BF(u1t, 256);

    // ---------- aggregation: half-wave hw aggregates nodes row0+hw*8 .. +7 into buf ----------
    {
        int hw = (wave << 1) | (lane >> 5);     // 0..15
        int sl = lane & 31;
        int i0 = sl * 4;                        // 4 channels per lane
        f32x2 w01, w23;
        { float4 w4 = *(const float4*)(w1c + i0);
          w01.x = w4.x; w01.y = w4.y; w23.x = w4.z; w23.y = w4.w; }
        const unsigned short* Qb = PQin + 128 + i0;
        for (int v = 0; v < 8; ++v) {
            int n = row0 + hw*8 + v;
            f32x2 p01, p23;
            { ushort4 p4 = *(const ushort4*)(PQin + (long)n*256 + i0);
              p01.x = bf2f(p4.x); p01.y = bf2f(p4.y); p23.x = bf2f(p4.z); p23.y = bf2f(p4.w); }
            int s = offs[n], c = cnt[n];
            f32x2 za = {0.f, 0.f};
            f32x2 a01 = za, a23 = za, b01 = za, b23 = za;
            int j = 0;
            for (; j + 4 <= c; j += 4) {
                uint4 sa = *(const uint4*)(sorted + s + j);
                uint2 q0 = *(const uint2*)(Qb + (long)(sa.x & 0xffffu)*256);
                uint2 q1 = *(const uint2*)(Qb + (long)(sa.y & 0xffffu)*256);
                uint2 q2 = *(const uint2*)(Qb + (long)(sa.z & 0xffffu)*256);
                uint2 q3 = *(const uint2*)(Qb + (long)(sa.w & 0xffffu)*256);
                AGG_EDGE(sa.x, q0, a); AGG_EDGE(sa.y, q1, b);
                AGG_EDGE(sa.z, q2, a); AGG_EDGE(sa.w, q3, b);
            }
            for (; j < c; ++j) {
                unsigned e0 = sorted[s + j];
                uint2 q0 = *(const uint2*)(Qb + (long)(e0 & 0xffffu)*256);
                AGG_EDGE(e0, q0, a);
            }
            a01 += b01; a23 += b23;
            float inv = 1.0f / fmaxf((float)c, 1.0f);
            ushort4 o;
            o.x = f2bf(a01.x * inv); o.y = f2bf(a01.y * inv);
            o.z = f2bf(a23.x * inv); o.w = f2bf(a23.y * inv);
            *(ushort4*)(&buf[hw*8 + v][i0]) = o;
        }
    }
    // hA from buf: rows 16*wave..+15 were written only by this wave's two half-waves;
    // same-wave LDS ops are in-order -> no barrier needed
    short8 hA[4];
    LOADA_BUF16(hA);

    // ---------- stage A: u_hid = relu(x@U1a + Hb@W2U1b + mask*c1 + ub1) -> buf ----------
    ZACC8();
    MFMA_R(xA);
    STAGE_BF(wt2l, 128);  MFMA_R(hA);
    {
        float mask[4];
        #pragma unroll
        for (int r = 0; r < 4; ++r)
            mask[r] = (cnt[grow0 + quad*4 + r] > 0) ? 1.f : 0.f;
        #pragma unroll
        for (int t = 0; t < 8; ++t) {
            int col = t*16 + cl;
            float bv = ub1[col], cv = c1l[col];
            #pragma unroll
            for (int r = 0; r < 4; ++r)
                buf[wrow + quad*4 + r][col] = f2bf(fmaxf(acc[t][r] + mask[r]*cv + bv, 0.f));
        }
    }

    // ---------- stage B: y = u_hid@U2 + ub2 ; x' = relu(LN(y)*g+b) -> global + buf ----------
    short8 aB[4];
    LOADA_BUF16(aB);
    ZACC8();
    STAGE_BF(u2t, 128);   MFMA_R(aB);
    float colacc[8];
    {
        float rs[4] = {0,0,0,0}, rq[4] = {0,0,0,0};
        #pragma unroll
        for (int t = 0; t < 8; ++t) {
            float bv = ub2[t*16 + cl];
            #pragma unroll
            for (int r = 0; r < 4; ++r) {
                acc[t][r] += bv; rs[r] += acc[t][r]; rq[r] += acc[t][r]*acc[t][r];
            }
        }
        #pragma unroll
        for (int o = 1; o < 16; o <<= 1) {
            #pragma unroll
            for (int r = 0; r < 4; ++r) {
                rs[r] += __shfl_xor(rs[r], o); rq[r] += __shfl_xor(rq[r], o);
            }
        }
        float mu[4], iv[4];
        #pragma unroll
        for (int r = 0; r < 4; ++r) {
            mu[r] = rs[r] * (1.f/128.f);
            iv[r] = rsqrtf(rq[r] * (1.f/128.f) - mu[r]*mu[r] + 1e-5f);
        }
        #pragma unroll
        for (int t = 0; t < 8; ++t) {
            int col = t*16 + cl;
            float gv = lng[col], bb = lnb[col];
            float s = 0.f;
            #pragma unroll
            for (int r = 0; r < 4; ++r) {
                float y0 = fmaxf((acc[t][r] - mu[r]) * iv[r] * gv + bb, 0.f);
                unsigned short h0 = f2bf(y0);
                int g0 = grow0 + quad*4 + r;
                if (g0 < NNODES) { u_in[(long)g0*256 + col] = h0; s += y0; }
                buf[wrow + quad*4 + r][col] = h0;
            }
            colacc[t] = s;
        }
    }

    if (w1abt) {
        // ---------- stage C: PQ' = x'@W1ab' (+b1' on P half) -> PQout (other buffer) ----------
        LOADA_BUF16(aB);
        #pragma unroll
        for (int half = 0; half < 2; ++half) {
            ZACC8();
            STAGE_BF(w1abt + half*16384, 128);
            MFMA_R(aB);
            #pragma unroll
            for (int t = 0; t < 8; ++t) {
                int col = t*16 + cl;
                float bv = (half == 0) ? mb1n[col] : 0.f;
                #pragma unroll
                for (int r = 0; r < 4; ++r) {
                    int g0 = grow0 + quad*4 + r;
                    PQout[(long)g0*256 + half*128 + col] = f2bf(acc[t][r] + bv);
                }
            }
        }
    } else {
        // ---------- last layer: block-reduce column sums of x' into sumv ----------
        #pragma unroll
        for (int t = 0; t < 8; ++t) {
            colacc[t] += __shfl_xor(colacc[t], 16);
            colacc[t] += __shfl_xor(colacc[t], 32);
        }
        float* red = (float*)&buf[0][0];
        __syncthreads();
        if (lane < 16) {
            #pragma unroll
            for (int t = 0; t < 8; ++t) red[wave*128 + t*16 + lane] = colacc[t];
        }
        __syncthreads();
        if (tid < 128) {
            float s = 0.f;
            #pragma unroll
            for (int w = 0; w < 8; ++w) s += red[w*128 + tid];
            atomicAdd(&sumv[tid], s);
        }
    }
}

// ---- final tiny MLP on the mean (fp32) ----
__global__ __launch_bounds__(128) void final_k(
    const float* __restrict__ sum, const float* __restrict__ W1, const float* __restrict__ b1,
    const float* __restrict__ W2, const float* __restrict__ b2, float* __restrict__ out)
{
    __shared__ float gbuf[128], hbuf[128];
    int t = threadIdx.x;
    gbuf[t] = sum[t] * (1.f / 50000.f);
    __syncthreads();
    float a = b1[t];
    for (int k = 0; k < 128; ++k) a += gbuf[k] * W1[k*128 + t];
    hbuf[t] = fmaxf(a, 0.f);
    __syncthreads();
    float o = b2[t];
    for (int k = 0; k < 128; ++k) o += hbuf[k] * W2[k*128 + t];
    out[t] = o;
}

extern "C" void kernel_launch(void* const* d_in, const int* in_sizes, int n_in,
                              void* d_out, int out_size, void* d_ws, size_t ws_size,
                              hipStream_t stream)
{
    const float* node_feat = (const float*)d_in[0];
    const float* edge_attr = (const float*)d_in[1];
    const float* enc_W  = (const float*)d_in[2];
    const float* enc_b  = (const float*)d_in[3];
    const float* mlp_W1 = (const float*)d_in[4];
    const float* mlp_b1 = (const float*)d_in[5];
    const float* mlp_W2 = (const float*)d_in[6];
    const float* mlp_b2 = (const float*)d_in[7];
    const float* upd_W1 = (const float*)d_in[8];
    const float* upd_b1 = (const float*)d_in[9];
    const float* upd_W2 = (const float*)d_in[10];
    const float* upd_b2 = (const float*)d_in[11];
    const float* ln_g   = (const float*)d_in[12];
    const float* ln_b   = (const float*)d_in[13];
    const float* out_W1 = (const float*)d_in[14];
    const float* out_b1 = (const float*)d_in[15];
    const float* out_W2 = (const float*)d_in[16];
    const float* out_b2 = (const float*)d_in[17];
    const int* edge_index = (const int*)d_in[18];
    const int* e_src = edge_index;
    const int* e_dst = edge_index + NEDGES;

    // workspace layout (padded node rows = 50048; scan arrays padded to 50176)
    char* ws = (char*)d_ws;
    unsigned short* u_in = (unsigned short*)(ws + 0);          // [50048][256] bf16: [x | scratch]
    unsigned short* PQ0  = (unsigned short*)(ws + 25624576);   // [50048][256] bf16 (even layers)
    unsigned short* PQ1  = (unsigned short*)(ws + 51249152);   // [50048][256] bf16 (odd layers)
    unsigned int* sorted = (unsigned int*)(ws + 76873728);     // [800000] packed {bf16 ea | u16 src}
    float* sumv          = (float*)(ws + 80073728);            // [128] (adjacent to cnt: one memset)
    int* cnt             = (int*)(ws + 80074240);              // [50176]
    int* offs            = (int*)(ws + 80274944);              // [50176]
    int* btot            = (int*)(ws + 80475648);              // [64]
    unsigned short* wt   = (unsigned short*)(ws + 80476160);   // [3*WPL] bf16 weights
    unsigned short* wt2  = (unsigned short*)(ws + 81065984);   // [3*16384] bf16 (W2@U1b)^T
    float* c1f           = (float*)(ws + 81164288);            // [3*128] b2@U1b
    int* rank            = (int*)(ws + 81165824);              // [800000] edge rank in dst bucket
    unsigned short* PQb[2] = { PQ0, PQ1 };

    hipMemsetAsync(sumv, 0, 512 + NPAD*4, stream);   // zeroes sumv + cnt in one launch
    // merged: hist (blocks 0..3124) + weight cvt (blocks 3125..4276)
    cvt_hist_k<<<4277, 256, 0, stream>>>(mlp_W1, mlp_W2, upd_W1, upd_W2, wt,
                                         e_dst, cnt, rank);
    // merged: scan1 (49 blocks) + prep (3 blocks)
    scan1prep_k<<<52, 256, 0, stream>>>(cnt, offs, btot, wt, mlp_b2, wt2, c1f);
    scan23_k<<<49, 256, 0, stream>>>(btot, offs);

    // merged: encoder+PQ0 (391 blocks) + edge placement (1563 blocks)
    enc_place_k<<<1954, 512, 0, stream>>>(node_feat, enc_W, enc_b, wt, mlp_b1,
                                          u_in, PQ0,
                                          e_src, e_dst, edge_attr, offs, rank, sorted);

    for (int l = 0; l < 3; ++l) {
        const unsigned short* u1t = wt + l*WPL + 49152;    // [128][256]
        const unsigned short* u2t = wt + l*WPL + 81920;    // [128][128]
        fused_layer_k<<<391, 512, 0, stream>>>(
            PQb[l & 1], sorted, offs, cnt,
            mlp_W1 + (l*257 + 256)*128,
            u1t, wt2 + (long)l*16384, u2t,
            (l < 2) ? (wt + (l+1)*WPL) : nullptr,
            c1f + l*128,
            upd_b1 + l*128, upd_b2 + l*128,
            ln_g + l*128, ln_b + l*128,
            (l < 2) ? (mlp_b1 + (l+1)*128) : nullptr,
            u_in, PQb[(l + 1) & 1], sumv);
    }
    final_k<<<1, 128, 0, stream>>>(sumv, out_W1, out_b1, out_W2, out_b2, (float*)d_out);
}

// Round 6
// 360.087 us; speedup vs baseline: 1.1054x; 1.1054x over previous
//
#include <hip/hip_runtime.h>
#include <stdint.h>

#define HID 128
#define NNODES 50000
#define NEDGES 800000
#define WPL 98304   // bf16 weight elems per layer in wt scratch
#define NPAD 50176  // padded node count (= 196*256 = 49*1024)

typedef __attribute__((ext_vector_type(8))) short short8;
typedef __attribute__((ext_vector_type(4))) float floatx4;
typedef __attribute__((ext_vector_type(2))) float f32x2;

__device__ __forceinline__ float bf2f(unsigned short h) {
    union { unsigned int u; float f; } v; v.u = ((unsigned int)h) << 16; return v.f;
}
__device__ __forceinline__ unsigned short f2bf(float f) {
    union { float f; unsigned int u; } v; v.f = f;
    unsigned int u = v.u;
    return (unsigned short)((u + 0x7fffu + ((u >> 16) & 1u)) >> 16);
}
// unpack 2 packed bf16 (one u32) -> f32x2
__device__ __forceinline__ f32x2 unpk2(unsigned int w) {
    union { unsigned int u; float f; } a, b;
    a.u = w << 16; b.u = w & 0xffff0000u;
    f32x2 r; r.x = a.f; r.y = b.f; return r;
}
__device__ __forceinline__ f32x2 pkmax0(f32x2 a) {
    f32x2 r; r.x = fmaxf(a.x, 0.f); r.y = fmaxf(a.y, 0.f); return r;
}

// ---- merged: convert all layer weights to bf16 (transposed [n][k]) + edge histogram ----
__global__ __launch_bounds__(256) void cvt_hist_k(
    const float* __restrict__ mW1, const float* __restrict__ mW2,
    const float* __restrict__ uW1, const float* __restrict__ uW2,
    unsigned short* __restrict__ wt,
    const int* __restrict__ dst, int* __restrict__ cnt, int* __restrict__ rank)
{
    if (blockIdx.x < 3125) {
        int e = blockIdx.x * 256 + threadIdx.x;
        rank[e] = atomicAdd(&cnt[dst[e]], 1);
        return;
    }
    int id = (blockIdx.x - 3125) * 256 + threadIdx.x;
    int l = id / WPL;
    int r = id - l * WPL;
    float v;
    if (r < 16384)      { int n = r >> 7, k = r & 127;                v = mW1[(l*257 + k)*128 + n]; }
    else if (r < 32768) { int q = r - 16384; int n = q >> 7, k = q & 127; v = mW1[(l*257 + 128 + k)*128 + n]; }
    else if (r < 49152) { int q = r - 32768; int n = q >> 7, k = q & 127; v = mW2[(l*128 + k)*128 + n]; }
    else if (r < 81920) { int q = r - 49152; int n = q >> 8, k = q & 255; v = uW1[(l*256 + k)*128 + n]; }
    else                { int q = r - 81920; int n = q >> 7, k = q & 127; v = uW2[(l*128 + k)*128 + n]; }
    wt[id] = f2bf(v);
}

// ---- merged scan1 (blocks 0..48) + prep (blocks 49..51) ----
__global__ __launch_bounds__(256) void scan1prep_k(
    const int* __restrict__ cnt, int* __restrict__ offs, int* __restrict__ btot,
    const unsigned short* __restrict__ wt, const float* __restrict__ mlp_b2,
    unsigned short* __restrict__ wt2, float* __restrict__ c1f)
{
    __shared__ unsigned short Bs[128][136];
    __shared__ int wsum[4];
    int tid = threadIdx.x, lane = tid & 63, wave = tid >> 6;
    if (blockIdx.x < 49) {
        int gid = blockIdx.x * 256 + tid;
        int4 v = ((const int4*)cnt)[gid];
        int tot = v.x + v.y + v.z + v.w;
        int sc = tot;
        #pragma unroll
        for (int o = 1; o < 64; o <<= 1) {
            int t = __shfl_up(sc, o);
            if (lane >= o) sc += t;
        }
        if (lane == 63) wsum[wave] = sc;
        __syncthreads();
        int woff = 0;
        #pragma unroll
        for (int i = 0; i < 3; ++i) if (i < wave) woff += wsum[i];
        int excl = woff + sc - tot;
        int4 o;
        o.x = excl; o.y = excl + v.x; o.z = o.y + v.y; o.w = o.z + v.z;
        ((int4*)offs)[gid] = o;
        if (tid == 255) btot[blockIdx.x] = woff + sc;
        return;
    }
    // ---- prep: wt2[l] = (W2@U1b)^T; c1f[l] = b2@U1b ----
    int l = blockIdx.x - 49;
    const unsigned short* u1bt = wt + l*WPL + 49152 + 128;  // A: [n][m], row stride 256
    const unsigned short* w2t  = wt + l*WPL + 32768;        // [m][kp], row stride 128
    int cl = lane & 15, quad = lane >> 4;
    int grow0 = wave * 32;
    floatx4 zero = {0.f,0.f,0.f,0.f};
    floatx4 acc0[8], acc1[8];
    short8 a0[4], a1[4];
    #pragma unroll
    for (int k = 0; k < 4; ++k) {
        a0[k] = *(const short8*)(u1bt + (long)(grow0 + cl)*256 + k*32 + quad*8);
        a1[k] = *(const short8*)(u1bt + (long)(grow0 + 16 + cl)*256 + k*32 + quad*8);
    }
    for (int i = 0; i < 64; ++i) {
        int idx = i*256 + tid;
        int m = idx >> 7, kp = idx & 127;
        Bs[kp][m] = w2t[m*128 + kp];
    }
    __syncthreads();
    #pragma unroll
    for (int t = 0; t < 8; ++t) { acc0[t] = zero; acc1[t] = zero; }
    #pragma unroll
    for (int k = 0; k < 4; ++k) {
        #pragma unroll
        for (int t = 0; t < 8; ++t) {
            short8 bf = *(const short8*)(&Bs[t*16 + cl][k*32 + quad*8]);
            acc0[t] = __builtin_amdgcn_mfma_f32_16x16x32_bf16(a0[k], bf, acc0[t], 0, 0, 0);
            acc1[t] = __builtin_amdgcn_mfma_f32_16x16x32_bf16(a1[k], bf, acc1[t], 0, 0, 0);
        }
    }
    #pragma unroll
    for (int t = 0; t < 8; ++t) {
        int col = t*16 + cl;
        #pragma unroll
        for (int r = 0; r < 4; ++r) {
            int n0 = grow0 + quad*4 + r, n1 = grow0 + 16 + quad*4 + r;
            wt2[(long)l*16384 + n0*128 + col] = f2bf(acc0[t][r]);
            wt2[(long)l*16384 + n1*128 + col] = f2bf(acc1[t][r]);
        }
    }
    if (tid < 128) {
        const float* mb2 = mlp_b2 + l*128;
        float acc = 0.f;
        for (int m = 0; m < 128; ++m)
            acc += mb2[m] * bf2f(u1bt[(long)tid*256 + m]);
        c1f[l*128 + tid] = acc;
    }
}

// merged scan2+3
__global__ __launch_bounds__(256) void scan23_k(const int* __restrict__ btot, int* __restrict__ offs)
{
    __shared__ int psh;
    int tid = threadIdx.x;
    if (tid < 64) {
        int v = (tid < blockIdx.x) ? btot[tid] : 0;   // blockIdx < 49
        #pragma unroll
        for (int o = 32; o > 0; o >>= 1) v += __shfl_down(v, o);
        if (tid == 0) psh = v;
    }
    __syncthreads();
    int gid = blockIdx.x * 256 + tid;
    int p = psh;
    int4 o = ((int4*)offs)[gid];
    o.x += p; o.y += p; o.z += p; o.w += p;
    ((int4*)offs)[gid] = o;
}

// ---- per-node aggregation: half-wave per node, 4 ch/lane, 8B gathers, packed f32 math ----
__global__ __launch_bounds__(512) void aggregate_k(
    const unsigned short* __restrict__ PQ,
    const unsigned int* __restrict__ sorted, const int* __restrict__ offs,
    const int* __restrict__ cnt,
    const float* __restrict__ w1c, unsigned short* __restrict__ Hb)
{
    int wave = threadIdx.x >> 6, lane = threadIdx.x & 63;
    int half = lane >> 5, sl = lane & 31;
    int n = blockIdx.x * 16 + wave * 2 + half;   // grid 3125*16 = 50000 exactly
    int i0 = sl * 4;
    f32x2 w01, w23;
    { float4 w4 = *(const float4*)(w1c + i0); w01.x = w4.x; w01.y = w4.y; w23.x = w4.z; w23.y = w4.w; }
    f32x2 p01, p23;
    { ushort4 p4 = *(const ushort4*)(PQ + (long)n*256 + i0);
      p01.x = bf2f(p4.x); p01.y = bf2f(p4.y); p23.x = bf2f(p4.z); p23.y = bf2f(p4.w); }
    int s = offs[n], c = cnt[n];
    const unsigned short* Qb = PQ + 128 + i0;
    f32x2 za = {0.f, 0.f};
    f32x2 a01 = za, a23 = za, b01 = za, b23 = za;
    int j = 0;
    for (; j + 8 <= c; j += 8) {
        uint4 sa = *(const uint4*)(sorted + s + j);
        uint4 sb = *(const uint4*)(sorted + s + j + 4);
        uint2 q0 = *(const uint2*)(Qb + (long)(sa.x & 0xffffu)*256);
        uint2 q1 = *(const uint2*)(Qb + (long)(sa.y & 0xffffu)*256);
        uint2 q2 = *(const uint2*)(Qb + (long)(sa.z & 0xffffu)*256);
        uint2 q3 = *(const uint2*)(Qb + (long)(sa.w & 0xffffu)*256);
        uint2 q4 = *(const uint2*)(Qb + (long)(sb.x & 0xffffu)*256);
        uint2 q5 = *(const uint2*)(Qb + (long)(sb.y & 0xffffu)*256);
        uint2 q6 = *(const uint2*)(Qb + (long)(sb.z & 0xffffu)*256);
        uint2 q7 = *(const uint2*)(Qb + (long)(sb.w & 0xffffu)*256);
        { float vf; { union { unsigned int u; float f; } t_; t_.u = sa.x & 0xffff0000u; vf = t_.f; }
          f32x2 vv; vv.x = vf; vv.y = vf;
          a01 += pkmax0(p01 + unpk2(q0.x) + vv*w01); a23 += pkmax0(p23 + unpk2(q0.y) + vv*w23); }
        { float vf; { union { unsigned int u; float f; } t_; t_.u = sa.y & 0xffff0000u; vf = t_.f; }
          f32x2 vv; vv.x = vf; vv.y = vf;
          b01 += pkmax0(p01 + unpk2(q1.x) + vv*w01); b23 += pkmax0(p23 + unpk2(q1.y) + vv*w23); }
        { float vf; { union { unsigned int u; float f; } t_; t_.u = sa.z & 0xffff0000u; vf = t_.f; }
          f32x2 vv; vv.x = vf; vv.y = vf;
          a01 += pkmax0(p01 + unpk2(q2.x) + vv*w01); a23 += pkmax0(p23 + unpk2(q2.y) + vv*w23); }
        { float vf; { union { unsigned int u; float f; } t_; t_.u = sa.w & 0xffff0000u; vf = t_.f; }
          f32x2 vv; vv.x = vf; vv.y = vf;
          b01 += pkmax0(p01 + unpk2(q3.x) + vv*w01); b23 += pkmax0(p23 + unpk2(q3.y) + vv*w23); }
        { float vf; { union { unsigned int u; float f; } t_; t_.u = sb.x & 0xffff0000u; vf = t_.f; }
          f32x2 vv; vv.x = vf; vv.y = vf;
          a01 += pkmax0(p01 + unpk2(q4.x) + vv*w01); a23 += pkmax0(p23 + unpk2(q4.y) + vv*w23); }
        { float vf; { union { unsigned int u; float f; } t_; t_.u = sb.y & 0xffff0000u; vf = t_.f; }
          f32x2 vv; vv.x = vf; vv.y = vf;
          b01 += pkmax0(p01 + unpk2(q5.x) + vv*w01); b23 += pkmax0(p23 + unpk2(q5.y) + vv*w23); }
        { float vf; { union { unsigned int u; float f; } t_; t_.u = sb.z & 0xffff0000u; vf = t_.f; }
          f32x2 vv; vv.x = vf; vv.y = vf;
          a01 += pkmax0(p01 + unpk2(q6.x) + vv*w01); a23 += pkmax0(p23 + unpk2(q6.y) + vv*w23); }
        { float vf; { union { unsigned int u; float f; } t_; t_.u = sb.w & 0xffff0000u; vf = t_.f; }
          f32x2 vv; vv.x = vf; vv.y = vf;
          b01 += pkmax0(p01 + unpk2(q7.x) + vv*w01); b23 += pkmax0(p23 + unpk2(q7.y) + vv*w23); }
    }
    for (; j + 4 <= c; j += 4) {
        uint4 sa = *(const uint4*)(sorted + s + j);
        uint2 q0 = *(const uint2*)(Qb + (long)(sa.x & 0xffffu)*256);
        uint2 q1 = *(const uint2*)(Qb + (long)(sa.y & 0xffffu)*256);
        uint2 q2 = *(const uint2*)(Qb + (long)(sa.z & 0xffffu)*256);
        uint2 q3 = *(const uint2*)(Qb + (long)(sa.w & 0xffffu)*256);
        { float vf; { union { unsigned int u; float f; } t_; t_.u = sa.x & 0xffff0000u; vf = t_.f; }
          f32x2 vv; vv.x = vf; vv.y = vf;
          a01 += pkmax0(p01 + unpk2(q0.x) + vv*w01); a23 += pkmax0(p23 + unpk2(q0.y) + vv*w23); }
        { float vf; { union { unsigned int u; float f; } t_; t_.u = sa.y & 0xffff0000u; vf = t_.f; }
          f32x2 vv; vv.x = vf; vv.y = vf;
          b01 += pkmax0(p01 + unpk2(q1.x) + vv*w01); b23 += pkmax0(p23 + unpk2(q1.y) + vv*w23); }
        { float vf; { union { unsigned int u; float f; } t_; t_.u = sa.z & 0xffff0000u; vf = t_.f; }
          f32x2 vv; vv.x = vf; vv.y = vf;
          a01 += pkmax0(p01 + unpk2(q2.x) + vv*w01); a23 += pkmax0(p23 + unpk2(q2.y) + vv*w23); }
        { float vf; { union { unsigned int u; float f; } t_; t_.u = sa.w & 0xffff0000u; vf = t_.f; }
          f32x2 vv; vv.x = vf; vv.y = vf;
          b01 += pkmax0(p01 + unpk2(q3.x) + vv*w01); b23 += pkmax0(p23 + unpk2(q3.y) + vv*w23); }
    }
    for (; j < c; ++j) {
        unsigned e0 = sorted[s + j];
        uint2 q0 = *(const uint2*)(Qb + (long)(e0 & 0xffffu)*256);
        { float vf; { union { unsigned int u; float f; } t_; t_.u = e0 & 0xffff0000u; vf = t_.f; }
          f32x2 vv; vv.x = vf; vv.y = vf;
          a01 += pkmax0(p01 + unpk2(q0.x) + vv*w01); a23 += pkmax0(p23 + unpk2(q0.y) + vv*w23); }
    }
    a01 += b01; a23 += b23;
    float inv = 1.0f / fmaxf((float)c, 1.0f);
    ushort4 o;
    o.x = f2bf(a01.x * inv); o.y = f2bf(a01.y * inv);
    o.z = f2bf(a23.x * inv); o.w = f2bf(a23.y * inv);
    *(ushort4*)(Hb + (long)n*128 + i0) = o;
}

// ======== macros: 128-row blocks, 8 waves (512 thr), M=16/wave ========
#define STAGE_B64(ptr, stride, k0) { __syncthreads(); _Pragma("unroll") \
    for (int it = 0; it < 4; ++it) { int idx = it*2048 + tid*4; int r = idx >> 6, c = idx & 63; \
        *(ushort4*)(&Bs[r][c]) = *(const ushort4*)((ptr) + (long)r*(stride) + (k0) + c); } \
    __syncthreads(); }
#define MFMA_L64(k0) { _Pragma("unroll") for (int kk = 0; kk < 64; kk += 32) { \
    short8 a0 = *(const short8*)(&buf[wrow + cl][(k0) + kk + quad*8]); \
    _Pragma("unroll") for (int t = 0; t < 8; ++t) { \
        short8 bf = *(const short8*)(&Bs[t*16 + cl][kk + quad*8]); \
        acc[t] = __builtin_amdgcn_mfma_f32_16x16x32_bf16(a0, bf, acc[t], 0, 0, 0); } } }
#define MFMA_R(p) { _Pragma("unroll") for (int k4 = 0; k4 < 4; ++k4) { \
    _Pragma("unroll") for (int t = 0; t < 8; ++t) { \
        short8 bf = *(const short8*)(&Bs[t*16 + cl][k4*32 + quad*8]); \
        acc[t] = __builtin_amdgcn_mfma_f32_16x16x32_bf16(p[k4], bf, acc[t], 0, 0, 0); } } }
#define LOADA_BUF16(d) { _Pragma("unroll") for (int k4 = 0; k4 < 4; ++k4) \
    d[k4] = *(const short8*)(&buf[wrow + cl][k4*32 + quad*8]); }
#define PRELOAD_A16(d, aptr, astride) { _Pragma("unroll") \
    for (int k = 0; k < 4; ++k) \
        d[k] = *(const short8*)((aptr) + (long)(grow0 + cl)*(astride) + k*32 + quad*8); }
#define ZACC8() { _Pragma("unroll") for (int t = 0; t < 8; ++t) acc[t] = zero; }
// async staging: global -> regs (issue early), regs -> LDS (late, before barrier)
#define LOADG(ptr, stride) { _Pragma("unroll") for (int it = 0; it < 8; ++it) { \
    int q = it*512 + tid; int r = q >> 5, c = (q & 31)*4; \
    G[it] = *(const ushort4*)((ptr) + (long)r*(stride) + c); } }
#define WRITES() { _Pragma("unroll") for (int it = 0; it < 8; ++it) { \
    int q = it*512 + tid; int r = q >> 5, c = (q & 31)*4; \
    *(ushort4*)(&Bs[r][c]) = G[it]; } }

// ---- fused encoder + PQ0 (blocks 0..390) + edge placement (blocks 391..1953) ----
__global__ __launch_bounds__(512, 4) void enc_place_k(
    const float* __restrict__ nf, const float* __restrict__ encW, const float* __restrict__ encb,
    const unsigned short* __restrict__ w1abt,   // [256][128] layer-0
    const float* __restrict__ mb1,
    unsigned short* __restrict__ u_in, unsigned short* __restrict__ PQ,
    const int* __restrict__ esrc, const int* __restrict__ edst,
    const float* __restrict__ ea, const int* __restrict__ offs,
    const int* __restrict__ rank, unsigned int* __restrict__ sorted)
{
    __shared__ unsigned short Bs[128][72];
    __shared__ unsigned short buf[128][136];
    int tid = threadIdx.x;
    if (blockIdx.x >= 391) {
        int e = (blockIdx.x - 391) * 512 + tid;
        if (e < NEDGES) {
            int d = edst[e];
            int pos = offs[d] + rank[e];
            unsigned pr = ((unsigned)f2bf(ea[e]) << 16) | (unsigned)esrc[e];
            sorted[pos] = pr;
        }
        return;
    }
    int wave = tid >> 6, lane = tid & 63;
    int cl = lane & 15, quad = lane >> 4;
    int row0 = blockIdx.x * 128;
    int wrow = wave * 16;
    int grow0 = row0 + wrow;
    floatx4 zero = {0.f,0.f,0.f,0.f};
    floatx4 acc[8];

    float* nfs = (float*)&Bs[0][0];             // 640 floats = 2.5 KB (aliased; used before staging)
    for (int i = tid; i < 640; i += 512) {
        int gi = row0*5 + i;
        nfs[i] = (gi < NNODES*5) ? nf[gi] : 0.f;
    }
    __syncthreads();
    {
        int c = tid & 127, h = tid >> 7;       // h in 0..3, 32 rows each
        float w0 = encW[c], w1 = encW[128 + c], w2 = encW[256 + c], w3 = encW[384 + c], w4 = encW[512 + c];
        float bb = encb[c];
        for (int rr = 0; rr < 32; ++rr) {
            int r = h*32 + rr;
            float a = bb + nfs[r*5]*w0 + nfs[r*5+1]*w1 + nfs[r*5+2]*w2
                         + nfs[r*5+3]*w3 + nfs[r*5+4]*w4;
            unsigned short hv = f2bf(a);
            buf[r][c] = hv;
            int grow = row0 + r;
            if (grow < NNODES) u_in[(long)grow*256 + c] = hv;
        }
    }
    #pragma unroll
    for (int half = 0; half < 2; ++half) {
        ZACC8();
        STAGE_B64(w1abt + half*16384, 128, 0);   MFMA_L64(0);
        STAGE_B64(w1abt + half*16384, 128, 64);  MFMA_L64(64);
        #pragma unroll
        for (int t = 0; t < 8; ++t) {
            int col = t*16 + cl;
            float bv = (half == 0) ? mb1[col] : 0.f;
            #pragma unroll
            for (int r = 0; r < 4; ++r) {
                int g0 = grow0 + quad*4 + r;
                PQ[(long)g0*256 + half*128 + col] = f2bf(acc[t][r] + bv);
            }
        }
    }
}

// ---- fused per-layer update: 128-row blocks, 8 waves, async (reg-prefetch) B staging ----
__global__ __launch_bounds__(512, 4) void fused_update_k(
    const unsigned short* __restrict__ Hb,      // [50048][128]
    const unsigned short* __restrict__ u1t,     // [128][256] (U1^T; k cols 0..128 = U1a)
    const unsigned short* __restrict__ wt2l,    // [128][128] (W2@U1b)^T
    const unsigned short* __restrict__ u2t,     // [128][128]
    const unsigned short* __restrict__ w1abt,   // [256][128] next-layer, or null
    const float* __restrict__ c1l,              // [128] b2@U1b
    const int* __restrict__ cnt,
    const float* __restrict__ ub1, const float* __restrict__ ub2,
    const float* __restrict__ lng, const float* __restrict__ lnb,
    const float* __restrict__ mb1n,             // next-layer b1, or null
    unsigned short* __restrict__ u_in,          // x at stride 256 (read cols 0:128, write x')
    unsigned short* __restrict__ PQ,            // [50048][256] out (if w1abt)
    float* __restrict__ sumv)                   // [128] colsum out (if !w1abt)
{
    __shared__ unsigned short Bs[128][136];     // staged B (N=128 x K=128, +pad)
    __shared__ unsigned short buf[128][136];    // inter-stage A (wave-row-private)
    int tid = threadIdx.x, wave = tid >> 6, lane = tid & 63;
    int cl = lane & 15, quad = lane >> 4;
    int row0 = blockIdx.x * 128;
    int wrow = wave * 16;
    int grow0 = row0 + wrow;
    floatx4 zero = {0.f,0.f,0.f,0.f};
    floatx4 acc[8];
    ushort4 G[8];

    // issue stage-A1 weight loads first; A-preloads overlap
    LOADG(u1t, 256);
    short8 hA[4], xA[4];
    PRELOAD_A16(hA, Hb, 128);
    PRELOAD_A16(xA, u_in, 256);

    // ---------- stage A: u_hid = relu(x@U1a + Hb@W2U1b + mask*c1 + ub1) -> buf ----------
    ZACC8();
    WRITES();                 // u1t -> LDS (waits loads)
    LOADG(wt2l, 128);         // prefetch next under this stage's MFMA
    __syncthreads();
    MFMA_R(xA);
    __syncthreads();          // all waves done reading Bs(u1t)
    WRITES();                 // wt2l -> LDS
    LOADG(u2t, 128);
    __syncthreads();
    MFMA_R(hA);
    {
        float mask[4];
        #pragma unroll
        for (int r = 0; r < 4; ++r)
            mask[r] = (cnt[grow0 + quad*4 + r] > 0) ? 1.f : 0.f;
        #pragma unroll
        for (int t = 0; t < 8; ++t) {
            int col = t*16 + cl;
            float bv = ub1[col], cv = c1l[col];
            #pragma unroll
            for (int r = 0; r < 4; ++r)
                buf[wrow + quad*4 + r][col] = f2bf(fmaxf(acc[t][r] + mask[r]*cv + bv, 0.f));
        }
    }

    // ---------- stage B: y = u_hid@U2 + ub2 ; x' = relu(LN(y)*g+b) -> global + buf ----------
    short8 aB[4];
    LOADA_BUF16(aB);          // same-wave rows; in-order LDS, no barrier needed
    __syncthreads();          // all waves done reading Bs(wt2l)
    WRITES();                 // u2t -> LDS
    if (w1abt) LOADG(w1abt, 128);
    __syncthreads();
    ZACC8();
    MFMA_R(aB);
    float colacc[8];
    {
        float rs[4] = {0,0,0,0}, rq[4] = {0,0,0,0};
        #pragma unroll
        for (int t = 0; t < 8; ++t) {
            float bv = ub2[t*16 + cl];
            #pragma unroll
            for (int r = 0; r < 4; ++r) {
                acc[t][r] += bv; rs[r] += acc[t][r]; rq[r] += acc[t][r]*acc[t][r];
            }
        }
        #pragma unroll
        for (int o = 1; o < 16; o <<= 1) {
            #pragma unroll
            for (int r = 0; r < 4; ++r) {
                rs[r] += __shfl_xor(rs[r], o); rq[r] += __shfl_xor(rq[r], o);
            }
        }
        float mu[4], iv[4];
        #pragma unroll
        for (int r = 0; r < 4; ++r) {
            mu[r] = rs[r] * (1.f/128.f);
            iv[r] = rsqrtf(rq[r] * (1.f/128.f) - mu[r]*mu[r] + 1e-5f);
        }
        #pragma unroll
        for (int t = 0; t < 8; ++t) {
            int col = t*16 + cl;
            float gv = lng[col], bb = lnb[col];
            float s = 0.f;
            #pragma unroll
            for (int r = 0; r < 4; ++r) {
                float y0 = fmaxf((acc[t][r] - mu[r]) * iv[r] * gv + bb, 0.f);
                unsigned short h0 = f2bf(y0);
                int g0 = grow0 + quad*4 + r;
                if (g0 < NNODES) { u_in[(long)g0*256 + col] = h0; s += y0; }
                buf[wrow + quad*4 + r][col] = h0;
            }
            colacc[t] = s;
        }
    }

    if (w1abt) {
        // ---------- stage C: PQ' = x'@W1ab' (+b1' on P half) ----------
        LOADA_BUF16(aB);      // x' (same-wave rows)
        __syncthreads();      // all waves done reading Bs(u2t)
        WRITES();             // w1abt half0 -> LDS
        LOADG(w1abt + 16384, 128);
        __syncthreads();
        ZACC8();
        MFMA_R(aB);
        #pragma unroll
        for (int t = 0; t < 8; ++t) {
            int col = t*16 + cl;
            float bv = mb1n[col];
            #pragma unroll
            for (int r = 0; r < 4; ++r) {
                int g0 = grow0 + quad*4 + r;
                PQ[(long)g0*256 + col] = f2bf(acc[t][r] + bv);
            }
        }
        __syncthreads();      // done reading Bs(half0)
        WRITES();             // half1 -> LDS
        __syncthreads();
        ZACC8();
        MFMA_R(aB);
        #pragma unroll
        for (int t = 0; t < 8; ++t) {
            int col = t*16 + cl;
            #pragma unroll
            for (int r = 0; r < 4; ++r) {
                int g0 = grow0 + quad*4 + r;
                PQ[(long)g0*256 + 128 + col] = f2bf(acc[t][r]);
            }
        }
    } else {
        // ---------- last layer: block-reduce column sums of x' into sumv ----------
        #pragma unroll
        for (int t = 0; t < 8; ++t) {
            colacc[t] += __shfl_xor(colacc[t], 16);
            colacc[t] += __shfl_xor(colacc[t], 32);
        }
        float* red = (float*)&buf[0][0];
        __syncthreads();
        if (lane < 16) {
            #pragma unroll
            for (int t = 0; t < 8; ++t) red[wave*128 + t*16 + lane] = colacc[t];
        }
        __syncthreads();
        if (tid < 128) {
            float s = 0.f;
            #pragma unroll
            for (int w = 0; w < 8; ++w) s += red[w*128 + tid];
            atomicAdd(&sumv[tid], s);
        }
    }
}

// ---- final tiny MLP on the mean (fp32) ----
__global__ __launch_bounds__(128) void final_k(
    const float* __restrict__ sum, const float* __restrict__ W1, const float* __restrict__ b1,
    const float* __restrict__ W2, const float* __restrict__ b2, float* __restrict__ out)
{
    __shared__ float gbuf[128], hbuf[128];
    int t = threadIdx.x;
    gbuf[t] = sum[t] * (1.f / 50000.f);
    __syncthreads();
    float a = b1[t];
    for (int k = 0; k < 128; ++k) a += gbuf[k] * W1[k*128 + t];
    hbuf[t] = fmaxf(a, 0.f);
    __syncthreads();
    float o = b2[t];
    for (int k = 0; k < 128; ++k) o += hbuf[k] * W2[k*128 + t];
    out[t] = o;
}

extern "C" void kernel_launch(void* const* d_in, const int* in_sizes, int n_in,
                              void* d_out, int out_size, void* d_ws, size_t ws_size,
                              hipStream_t stream)
{
    const float* node_feat = (const float*)d_in[0];
    const float* edge_attr = (const float*)d_in[1];
    const float* enc_W  = (const float*)d_in[2];
    const float* enc_b  = (const float*)d_in[3];
    const float* mlp_W1 = (const float*)d_in[4];
    const float* mlp_b1 = (const float*)d_in[5];
    const float* mlp_W2 = (const float*)d_in[6];
    const float* mlp_b2 = (const float*)d_in[7];
    const float* upd_W1 = (const float*)d_in[8];
    const float* upd_b1 = (const float*)d_in[9];
    const float* upd_W2 = (const float*)d_in[10];
    const float* upd_b2 = (const float*)d_in[11];
    const float* ln_g   = (const float*)d_in[12];
    const float* ln_b   = (const float*)d_in[13];
    const float* out_W1 = (const float*)d_in[14];
    const float* out_b1 = (const float*)d_in[15];
    const float* out_W2 = (const float*)d_in[16];
    const float* out_b2 = (const float*)d_in[17];
    const int* edge_index = (const int*)d_in[18];
    const int* e_src = edge_index;
    const int* e_dst = edge_index + NEDGES;

    // workspace layout (padded node rows = 50048; scan arrays padded to 50176)
    char* ws = (char*)d_ws;
    unsigned short* u_in = (unsigned short*)(ws + 0);          // [50048][256] bf16: [x | scratch]
    unsigned short* PQ   = (unsigned short*)(ws + 25624576);   // [50048][256] bf16: [P | Q]
    unsigned short* Hb   = (unsigned short*)(ws + 51249152);   // [50048][128] bf16
    unsigned int* sorted = (unsigned int*)(ws + 64061440);     // [800000] packed {bf16 ea | u16 src}
    float* sumv          = (float*)(ws + 70460928);            // [128] (adjacent to cnt: one memset)
    int* cnt             = (int*)(ws + 70461440);              // [50176]
    int* offs            = (int*)(ws + 70662144);              // [50176]
    int* btot            = (int*)(ws + 70862848);              // [64]
    unsigned short* wt   = (unsigned short*)(ws + 70863360);   // [3*WPL] bf16 weights
    unsigned short* wt2  = (unsigned short*)(ws + 71453184);   // [3*16384] bf16 (W2@U1b)^T
    float* c1f           = (float*)(ws + 71551488);            // [3*128] b2@U1b
    int* rank            = (int*)(ws + 71553024);              // [800000] edge rank in dst bucket

    hipMemsetAsync(sumv, 0, 512 + NPAD*4, stream);   // zeroes sumv + cnt in one launch
    // merged: hist (blocks 0..3124) + weight cvt (blocks 3125..4276)
    cvt_hist_k<<<4277, 256, 0, stream>>>(mlp_W1, mlp_W2, upd_W1, upd_W2, wt,
                                         e_dst, cnt, rank);
    // merged: scan1 (49 blocks) + prep (3 blocks)
    scan1prep_k<<<52, 256, 0, stream>>>(cnt, offs, btot, wt, mlp_b2, wt2, c1f);
    scan23_k<<<49, 256, 0, stream>>>(btot, offs);

    // merged: encoder+PQ0 (391 blocks) + edge placement (1563 blocks)
    enc_place_k<<<1954, 512, 0, stream>>>(node_feat, enc_W, enc_b, wt, mlp_b1,
                                          u_in, PQ,
                                          e_src, e_dst, edge_attr, offs, rank, sorted);

    for (int l = 0; l < 3; ++l) {
        const unsigned short* u1t = wt + l*WPL + 49152;    // [128][256]
        const unsigned short* u2t = wt + l*WPL + 81920;    // [128][128]
        // Hb = inv_deg * segsum(relu(P[dst]+Q[src]+ea*w1c))  — half-wave per node, full TLP
        aggregate_k<<<3125, 512, 0, stream>>>(PQ, sorted, offs, cnt,
                                              mlp_W1 + (l*257 + 256)*128, Hb);
        // fused: u_hid (folded aggr) -> x' (LN) -> PQ for layer l+1 (or colsum on last layer)
        fused_update_k<<<391, 512, 0, stream>>>(
            Hb, u1t, wt2 + (long)l*16384, u2t,
            (l < 2) ? (wt + (l+1)*WPL) : nullptr,
            c1f + l*128, cnt,
            upd_b1 + l*128, upd_b2 + l*128,
            ln_g + l*128, ln_b + l*128,
            (l < 2) ? (mlp_b1 + (l+1)*128) : nullptr,
            u_in, PQ, sumv);
    }
    final_k<<<1, 128, 0, stream>>>(sumv, out_W1, out_b1, out_W2, out_b2, (float*)d_out);
}